// Round 4
// baseline (554.446 us; speedup 1.0000x reference)
//
#include <hip/hip_runtime.h>
#include <math.h>

typedef unsigned int u32;
typedef unsigned short u16;

__device__ __forceinline__ u16 f2bf(float f){
  union{float f;u32 u;}v; v.f=f;
  u32 u=v.u; u += 0x7fffu + ((u>>16)&1u);
  return (u16)(u>>16);
}
__device__ __forceinline__ float gelu_exact(float z){
  return 0.5f*z*(1.f + erff(z*0.7071067811865476f));
}
// load 8 bf16 factors (one d-record, 16B) from LDS, widen to fp32
__device__ __forceinline__ void ld8(const uint4* fq, int arr, int d, float* o){
  uint4 v = fq[arr*1024 + d];
  union{u32 i;float f;}c;
  c.i = v.x<<16;        o[0]=c.f;  c.i = v.x&0xffff0000u; o[1]=c.f;
  c.i = v.y<<16;        o[2]=c.f;  c.i = v.y&0xffff0000u; o[3]=c.f;
  c.i = v.z<<16;        o[4]=c.f;  c.i = v.z&0xffff0000u; o[5]=c.f;
  c.i = v.w<<16;        o[6]=c.f;  c.i = v.w&0xffff0000u; o[7]=c.f;
}

// -------- K1: hT[col][b] = gelu_exact( LN(ada[b]) @ W1 + b1 )[col]  [1024,16] fp32 --------
// grid (32 col-chunks of 32, 16 batches), 256 thr; per-thread k-range 128 (8-way split).
__global__ __launch_bounds__(256) void k_hyper1(
    const float* __restrict__ ada, const float* __restrict__ lng, const float* __restrict__ lnb,
    const float* __restrict__ W1, const float* __restrict__ b1, float* __restrict__ hT)
{
  __shared__ float lns[1024];
  __shared__ float red[8];
  __shared__ float cmb[256];
  const int b = blockIdx.y;
  const int tid = threadIdx.x;
  float a4[4]; float s=0.f, s2=0.f;
  #pragma unroll
  for (int i=0;i<4;i++){
    float v = ada[(size_t)b*1024 + tid + 256*i];
    a4[i]=v; s+=v; s2+=v*v;
  }
  #pragma unroll
  for (int m=32;m>=1;m>>=1){ s += __shfl_xor(s,m,64); s2 += __shfl_xor(s2,m,64); }
  if ((tid&63)==0){ red[tid>>6]=s; red[4+(tid>>6)]=s2; }
  __syncthreads();
  s  = red[0]+red[1]+red[2]+red[3];
  s2 = red[4]+red[5]+red[6]+red[7];
  const float mu = s*(1.f/1024.f);
  const float rs = rsqrtf(s2*(1.f/1024.f) - mu*mu + 1e-5f);
  #pragma unroll
  for (int i=0;i<4;i++){
    int k = tid + 256*i;
    lns[k] = (a4[i]-mu)*rs*lng[k] + lnb[k];
  }
  __syncthreads();
  const int c = tid&31;
  const int kq = tid>>5;               // 8-way k split, 128 each
  const int col = (blockIdx.x<<5) + c;
  float acc = 0.f;
  #pragma unroll 8
  for (int k=kq*128; k<kq*128+128; k++)
    acc = fmaf(lns[k], W1[(size_t)k*1024 + col], acc);
  cmb[c*8 + kq] = acc;
  __syncthreads();
  if (tid < 32){
    float v = b1[(blockIdx.x<<5) + tid];
    #pragma unroll
    for (int q=0;q<8;q++) v += cmb[tid*8 + q];
    hT[(size_t)((blockIdx.x<<5) + tid)*16 + b] = gelu_exact(v);
  }
}

// -------- K2: w[b][col] = h[b] . W2[:,col] + b2[col]  [16,32768] fp32 --------
// grid 512 blocks x 256 thr: 64 cols x 4-way k-split (256 k each) -> 8 waves/CU.
// h operand via readfirstlane-uniform pointer -> s_load_dwordx16 (1 SMEM + 1 VMEM + 16 fma / iter).
__global__ __launch_bounds__(256) void k_hyper2(
    const float* __restrict__ hT, const float* __restrict__ W2, const float* __restrict__ b2,
    float* __restrict__ w)
{
  __shared__ float cmb[64*65];         // pad 65: write stride 65 floats -> conflict-free
  const int tid = threadIdx.x;
  const int c = tid&63;
  const int kq = tid>>6;               // == wave id, wave-uniform
  const int col = (blockIdx.x<<6) + c;
  const float* hbase = hT + (size_t)__builtin_amdgcn_readfirstlane(kq) * 256 * 16;
  float acc[16];
  #pragma unroll
  for (int i=0;i<16;i++) acc[i]=0.f;
  #pragma unroll 4
  for (int k=0;k<256;k++){
    float wv = W2[(size_t)(kq*256 + k)*32768 + col];
    const float* hk = hbase + k*16;    // uniform -> scalar loads
    #pragma unroll
    for (int bb=0;bb<16;bb++) acc[bb] = fmaf(hk[bb], wv, acc[bb]);
  }
  #pragma unroll
  for (int bb=0;bb<16;bb++) cmb[c*65 + kq*16 + bb] = acc[bb];
  __syncthreads();
  if (kq==0){
    float bv = b2[col];
    #pragma unroll
    for (int bb=0;bb<16;bb++)
      w[(size_t)bb*32768 + col] =
        cmb[c*65+bb] + cmb[c*65+16+bb] + cmb[c*65+32+bb] + cmb[c*65+48+bb] + bv;
  }
}

// -------- K3: fused LoRA chain + residual; fp32 in/out --------
// Factors in LDS as bf16 records [arr][d][8r]; lane reads d=l+64i -> 16B-stride b128, conflict-free.
__global__ __launch_bounds__(256) void k_lora(
    const float* __restrict__ x, const float* __restrict__ w, float* __restrict__ out)
{
  __shared__ __align__(16) u16 fsb[4*1024*8];   // 64 KB
  const int b = blockIdx.y;
  const int tid = threadIdx.x;
  const float* wb = w + (size_t)b*32768;
  for (int idx=tid; idx<32768; idx+=256)
    fsb[idx] = f2bf(wb[idx]);                   // idx == (arr*1024+d)*8+r already
  __syncthreads();
  const int l = tid&63;
  const int wv = tid>>6;
  const uint4* fq = (const uint4*)fsb;
  const size_t xbase = (size_t)b*1024*1024;

  for (int round=0; round<4; round++){
    const int t0 = blockIdx.x*32 + wv*8 + round*2;
    float xv[2][16];
    #pragma unroll
    for (int tt=0;tt<2;tt++){
      const size_t row = xbase + (size_t)(t0+tt)*1024;
      #pragma unroll
      for (int i=0;i<16;i++)
        xv[tt][i] = x[row + l + 64*i];
    }
    // phase A: y1[t][r] = sum_d x_d * a1[d][r]
    float y1[2][8];
    for (int tt=0;tt<2;tt++)
      for (int r=0;r<8;r++) y1[tt][r]=0.f;
    #pragma unroll
    for (int i=0;i<16;i++){
      float a[8]; ld8(fq, 0, l+64*i, a);
      #pragma unroll
      for (int tt=0;tt<2;tt++){
        #pragma unroll
        for (int r=0;r<8;r++) y1[tt][r] = fmaf(xv[tt][i], a[r], y1[tt][r]);
      }
    }
    #pragma unroll
    for (int m=32;m>=1;m>>=1){
      #pragma unroll
      for (int tt=0;tt<2;tt++){
        #pragma unroll
        for (int r=0;r<8;r++) y1[tt][r] += __shfl_xor(y1[tt][r], m, 64);
      }
    }
    // phase B: z_d = y1 . bb1[d]; y2[r] = sum_d gelu(z_d) * a2[d][r]
    float y2[2][8];
    for (int tt=0;tt<2;tt++)
      for (int r=0;r<8;r++) y2[tt][r]=0.f;
    #pragma unroll
    for (int i=0;i<16;i++){
      float p[8], q[8];
      ld8(fq, 1, l+64*i, p);
      ld8(fq, 2, l+64*i, q);
      #pragma unroll
      for (int tt=0;tt<2;tt++){
        float z = 0.f;
        #pragma unroll
        for (int r=0;r<8;r++) z = fmaf(y1[tt][r], p[r], z);
        float g = gelu_exact(z);
        #pragma unroll
        for (int r=0;r<8;r++) y2[tt][r] = fmaf(g, q[r], y2[tt][r]);
      }
    }
    #pragma unroll
    for (int m=32;m>=1;m>>=1){
      #pragma unroll
      for (int tt=0;tt<2;tt++){
        #pragma unroll
        for (int r=0;r<8;r++) y2[tt][r] += __shfl_xor(y2[tt][r], m, 64);
      }
    }
    // phase C: out_d = x_d + y2 . bb2[d]
    #pragma unroll
    for (int i=0;i<16;i++){
      float cc[8]; ld8(fq, 3, l+64*i, cc);
      #pragma unroll
      for (int tt=0;tt<2;tt++){
        float o = xv[tt][i];
        #pragma unroll
        for (int r=0;r<8;r++) o = fmaf(y2[tt][r], cc[r], o);
        out[xbase + (size_t)(t0+tt)*1024 + l + 64*i] = o;
      }
    }
  }
}

extern "C" void kernel_launch(void* const* d_in, const int* in_sizes, int n_in,
                              void* d_out, int out_size, void* d_ws, size_t ws_size,
                              hipStream_t stream){
  const float* x    = (const float*)d_in[0];
  const float* ada  = (const float*)d_in[1];
  const float* lng  = (const float*)d_in[2];
  const float* lnb  = (const float*)d_in[3];
  const float* W1   = (const float*)d_in[4];
  const float* b1   = (const float*)d_in[5];
  const float* W2   = (const float*)d_in[6];
  const float* b2   = (const float*)d_in[7];
  float* out = (float*)d_out;
  float* hT  = (float*)d_ws;                          // [1024,16] fp32 (64 KB)
  float* w   = (float*)((char*)d_ws + 65536);         // [16,32768] fp32 (2 MB)

  k_hyper1<<<dim3(32,16), 256, 0, stream>>>(ada, lng, lnb, W1, b1, hT);
  k_hyper2<<<dim3(512,1), 256, 0, stream>>>(hT, W2, b2, w);
  k_lora  <<<dim3(32,16), 256, 0, stream>>>(x, w, out);
}